// Round 1
// baseline (186.021 us; speedup 1.0000x reference)
//
#include <hip/hip_runtime.h>
#include <hip/hip_bf16.h>
#include <stdint.h>

// Problem constants
#define BATCH   8192
#define IN_DIM  256
#define OUT_DIM 256
#define NC      512
#define NORD    9              // order+1
#define KTOT    (NC * NORD)    // 4608

// ws layout (bytes)
#define OFF_MM  0u
#define OFF_X2  256u
#define OFF_C2  (OFF_X2 + BATCH * 4u)                 // 33024
#define OFF_D   35072u                                 // d[8192][512] f32
#define OFF_WT  (OFF_D + (size_t)BATCH * NC * 4u)      // Wt[256][4608] bf16
#define OFF_G   (OFF_WT + (size_t)OUT_DIM * KTOT * 2u) // G[8192][4608] bf16
// total ~94.7 MB

typedef __bf16 bf16x8 __attribute__((ext_vector_type(8)));
typedef float  f32x4  __attribute__((ext_vector_type(4)));

__device__ inline unsigned short f2bf(float f) {
  unsigned u = __float_as_uint(f);
  return (unsigned short)((u + 0x7FFFu + ((u >> 16) & 1u)) >> 16);
}

__device__ inline void gload_lds16(const void* g, void* l) {
  __builtin_amdgcn_global_load_lds(
      (const __attribute__((address_space(1))) unsigned int*)(uintptr_t)g,
      (__attribute__((address_space(3))) unsigned int*)(uint32_t)(uintptr_t)l,
      16, 0, 0);
}

__global__ void k_init_mm(unsigned* mm) {
  mm[0] = 0x7F800000u;  // +inf bits (min)
  mm[1] = 0u;           // 0.0 bits (max); distances >= 0
}

// one wave per row; K = IN_DIM = 256 floats
__global__ __launch_bounds__(64) void k_rowsq(const float* __restrict__ src,
                                              float* __restrict__ dst) {
  const int row  = blockIdx.x;
  const int lane = threadIdx.x;
  const float4 v = *(const float4*)(src + (size_t)row * IN_DIM + lane * 4);
  float s = v.x * v.x + v.y * v.y + v.z * v.z + v.w * v.w;
  #pragma unroll
  for (int m = 1; m < 64; m <<= 1) s += __shfl_xor(s, m, 64);
  if (lane == 0) dst[row] = s;
}

// 64x64 fp32 distance tile; also feeds global min/max atomics
__global__ __launch_bounds__(256) void k_dist(const float* __restrict__ x,
                                              const float* __restrict__ cen,
                                              const float* __restrict__ x2,
                                              const float* __restrict__ c2,
                                              float* __restrict__ d,
                                              unsigned* __restrict__ mm) {
  __shared__ float As[64][36];  // pad 36: bank stride 4 -> 2-way (free)
  __shared__ float Bs[64][36];
  const int tid = threadIdx.x;
  const int bm0 = blockIdx.x * 64, bc0 = blockIdx.y * 64;
  float acc[4][4] = {};
  for (int k0 = 0; k0 < IN_DIM; k0 += 32) {
    __syncthreads();
    #pragma unroll
    for (int it = 0; it < 2; ++it) {
      const int row = (tid >> 3) + it * 32;
      const int c4  = (tid & 7) * 4;
      *(float4*)&As[row][c4] = *(const float4*)(x   + (size_t)(bm0 + row) * IN_DIM + k0 + c4);
      *(float4*)&Bs[row][c4] = *(const float4*)(cen + (size_t)(bc0 + row) * IN_DIM + k0 + c4);
    }
    __syncthreads();
    const int r0 = tid >> 4, c0 = tid & 15;
    #pragma unroll
    for (int k4 = 0; k4 < 32; k4 += 4) {
      float4 a[4], b[4];
      #pragma unroll
      for (int i = 0; i < 4; ++i) a[i] = *(const float4*)&As[r0 + 16 * i][k4];
      #pragma unroll
      for (int j = 0; j < 4; ++j) b[j] = *(const float4*)&Bs[c0 + 16 * j][k4];
      #pragma unroll
      for (int i = 0; i < 4; ++i)
        #pragma unroll
        for (int j = 0; j < 4; ++j)
          acc[i][j] += a[i].x * b[j].x + a[i].y * b[j].y +
                       a[i].z * b[j].z + a[i].w * b[j].w;
    }
  }
  const int r0 = tid >> 4, c0 = tid & 15;
  float lmin = 1e30f, lmax = -1e30f;
  #pragma unroll
  for (int i = 0; i < 4; ++i) {
    const float xs = x2[bm0 + r0 + 16 * i];
    #pragma unroll
    for (int j = 0; j < 4; ++j) {
      float d2 = xs + c2[bc0 + c0 + 16 * j] - 2.0f * acc[i][j];
      float dd = sqrtf(fmaxf(d2, 0.0f));
      d[(size_t)(bm0 + r0 + 16 * i) * NC + bc0 + c0 + 16 * j] = dd;
      lmin = fminf(lmin, dd);
      lmax = fmaxf(lmax, dd);
    }
  }
  #pragma unroll
  for (int m = 1; m < 64; m <<= 1) {
    lmin = fminf(lmin, __shfl_xor(lmin, m, 64));
    lmax = fmaxf(lmax, __shfl_xor(lmax, m, 64));
  }
  __shared__ float rmin[4], rmax[4];
  const int wid = tid >> 6, lane = tid & 63;
  if (lane == 0) { rmin[wid] = lmin; rmax[wid] = lmax; }
  __syncthreads();
  if (tid == 0) {
    float m0 = fminf(fminf(rmin[0], rmin[1]), fminf(rmin[2], rmin[3]));
    float m1 = fmaxf(fmaxf(rmax[0], rmax[1]), fmaxf(rmax[2], rmax[3]));
    atomicMin(mm + 0, __float_as_uint(m0));  // nonneg floats: uint order == float order
    atomicMax(mm + 1, __float_as_uint(m1));
  }
}

// W[c][n][f] f32 -> Wt[f][c*9+n] bf16 (64x64 LDS transpose tiles)
__global__ __launch_bounds__(256) void k_prepw(const float* __restrict__ w,
                                               unsigned short* __restrict__ wt) {
  __shared__ float t[64][65];
  const int k0 = blockIdx.x * 64, f0 = blockIdx.y * 64;
  const int tid = threadIdx.x;
  const int c = tid & 63, rb = tid >> 6;  // 4 rows per pass
  #pragma unroll
  for (int i = 0; i < 16; ++i) {
    const int r = rb + 4 * i;
    t[r][c] = w[(size_t)(k0 + r) * OUT_DIM + f0 + c];
  }
  __syncthreads();
  #pragma unroll
  for (int i = 0; i < 16; ++i) {
    const int r = rb + 4 * i;
    wt[(size_t)(f0 + r) * KTOT + k0 + c] = f2bf(t[c][r]);
  }
}

// per (b,c): t, Legendre recurrence, write 9 bf16
__global__ __launch_bounds__(256) void k_basis(const float* __restrict__ d,
                                               const unsigned* __restrict__ mm,
                                               unsigned short* __restrict__ G) {
  const int gid = blockIdx.x * 256 + threadIdx.x;  // b*512 + c
  const float dmin = __uint_as_float(mm[0]);
  const float dmax = __uint_as_float(mm[1]);
  const float inv  = 2.0f / (dmax - dmin);
  const float tt   = (d[gid] - dmin) * inv - 1.0f;
  unsigned short o[NORD];
  float p0 = 1.0f, p1 = tt;
  o[0] = f2bf(p0);
  o[1] = f2bf(p1);
  #pragma unroll
  for (int n = 1; n <= 7; ++n) {
    const float p2 = ((2.0f * n + 1.0f) * tt * p1 - (float)n * p0) * (1.0f / (n + 1));
    o[n + 1] = f2bf(p2);
    p0 = p1;
    p1 = p2;
  }
  unsigned short* gp = G + (size_t)gid * NORD;  // (b*512+c)*9 == b*4608 + c*9
  #pragma unroll
  for (int n = 0; n < NORD; ++n) gp[n] = o[n];
}

__global__ __launch_bounds__(256) void k_zero(float4* __restrict__ out) {
  out[(size_t)blockIdx.x * 256 + threadIdx.x] = float4{0.f, 0.f, 0.f, 0.f};
}

// out[8192,256] += G[8192,4608] @ Wt[256,4608]^T ; bf16 MFMA, split-K=2
__global__ __launch_bounds__(256) void k_gemm(const unsigned short* __restrict__ G,
                                              const unsigned short* __restrict__ Wt,
                                              float* __restrict__ out) {
  __shared__ unsigned short As[128 * 64];  // 128 rows x 64 k, XOR-swizzled
  __shared__ unsigned short Bs[64 * 64];
  const int tid  = threadIdx.x;
  const int bm0  = blockIdx.x * 128;
  const int bn0  = blockIdx.y * 64;
  const int kb0  = blockIdx.z * (KTOT / 2);
  const int lane = tid & 63;
  const int wid  = tid >> 6;
  const int wm = wid >> 1, wn = wid & 1;  // 2x2 waves: 64x32 each
  f32x4 acc[4][2] = {};
  const char* gA = (const char*)G;
  const char* gB = (const char*)Wt;
  char* lA = (char*)As;
  char* lB = (char*)Bs;
  for (int step = 0; step < (KTOT / 2) / 64; ++step) {
    const int k0 = kb0 + step * 64;
    __syncthreads();
    // stage: linear LDS dest, inverse-swizzled global source (rule #21)
    #pragma unroll
    for (int p = 0; p < 4; ++p) {
      const int flat = p * 4096 + tid * 16;
      const int row = flat >> 7, cb = flat & 127;
      const int srcb = cb ^ ((row & 7) << 4);
      gload_lds16(gA + ((size_t)(bm0 + row) * KTOT + k0) * 2 + srcb, lA + flat);
    }
    #pragma unroll
    for (int p = 0; p < 2; ++p) {
      const int flat = p * 4096 + tid * 16;
      const int row = flat >> 7, cb = flat & 127;
      const int srcb = cb ^ ((row & 7) << 4);
      gload_lds16(gB + ((size_t)(bn0 + row) * KTOT + k0) * 2 + srcb, lB + flat);
    }
    __syncthreads();
    #pragma unroll
    for (int ks = 0; ks < 2; ++ks) {
      bf16x8 af[4], bfr[2];
      const int kb = ks * 64 + (lane >> 4) * 16;  // byte offset in row
      #pragma unroll
      for (int m = 0; m < 4; ++m) {
        const int row = wm * 64 + m * 16 + (lane & 15);
        af[m] = *(const bf16x8*)(lA + row * 128 + (kb ^ ((row & 7) << 4)));
      }
      #pragma unroll
      for (int n = 0; n < 2; ++n) {
        const int row = wn * 32 + n * 16 + (lane & 15);
        bfr[n] = *(const bf16x8*)(lB + row * 128 + (kb ^ ((row & 7) << 4)));
      }
      #pragma unroll
      for (int m = 0; m < 4; ++m)
        #pragma unroll
        for (int n = 0; n < 2; ++n)
          acc[m][n] = __builtin_amdgcn_mfma_f32_16x16x32_bf16(af[m], bfr[n], acc[m][n], 0, 0, 0);
    }
  }
  // epilogue: C/D layout col=lane&15, row=(lane>>4)*4+j (m89-verified)
  #pragma unroll
  for (int m = 0; m < 4; ++m) {
    const int row0 = bm0 + wm * 64 + m * 16 + (lane >> 4) * 4;
    #pragma unroll
    for (int n = 0; n < 2; ++n) {
      const int col = bn0 + wn * 32 + n * 16 + (lane & 15);
      #pragma unroll
      for (int j = 0; j < 4; ++j)
        atomicAdd(out + (size_t)(row0 + j) * OUT_DIM + col, acc[m][n][j]);
    }
  }
}

extern "C" void kernel_launch(void* const* d_in, const int* in_sizes, int n_in,
                              void* d_out, int out_size, void* d_ws, size_t ws_size,
                              hipStream_t stream) {
  const float* x   = (const float*)d_in[0];
  const float* cen = (const float*)d_in[1];
  const float* w   = (const float*)d_in[2];
  float* out = (float*)d_out;
  char* ws = (char*)d_ws;

  unsigned*       mm = (unsigned*)(ws + OFF_MM);
  float*          x2 = (float*)(ws + OFF_X2);
  float*          c2 = (float*)(ws + OFF_C2);
  float*          dd = (float*)(ws + OFF_D);
  unsigned short* wt = (unsigned short*)(ws + OFF_WT);
  unsigned short* G  = (unsigned short*)(ws + OFF_G);

  k_init_mm<<<1, 1, 0, stream>>>(mm);
  k_rowsq<<<BATCH, 64, 0, stream>>>(x, x2);
  k_rowsq<<<NC, 64, 0, stream>>>(cen, c2);
  k_dist<<<dim3(BATCH / 64, NC / 64), 256, 0, stream>>>(x, cen, x2, c2, dd, mm);
  k_prepw<<<dim3(KTOT / 64, OUT_DIM / 64), 256, 0, stream>>>(w, wt);
  k_basis<<<(BATCH * NC) / 256, 256, 0, stream>>>(dd, mm, G);
  k_zero<<<(BATCH * OUT_DIM) / (256 * 4), 256, 0, stream>>>((float4*)out);
  k_gemm<<<dim3(BATCH / 128, OUT_DIM / 64, 2), 256, 0, stream>>>(G, wt, out);
}

// Round 12
// 151.005 us; speedup vs baseline: 1.2319x; 1.2319x over previous
//
#include <hip/hip_runtime.h>
#include <hip/hip_bf16.h>
#include <stdint.h>

// Problem constants
#define BATCH   8192
#define IN_DIM  256
#define OUT_DIM 256
#define NC      512
#define NORD    9              // order+1
#define KTOT    (NC * NORD)    // 4608
#define KE      768            // extended K for 3-product split distance GEMM

// ws layout (bytes), all 256-aligned
#define OFF_MM  0u
#define OFF_X2  256u
#define OFF_C2  33024u
#define OFF_AE  35072u                                  // Aext[8192][768] bf16 = [xh|xl|xh]
#define OFF_BE  12617984u                               // Bext[512][768]  bf16 = [ch|ch|cl]
#define OFF_WT  13404416u                               // Wt[256][4608] bf16, K = n*512+c
#define OFF_D   15763712u                               // d[8192][512] f32
// end ~32.5 MB

typedef __bf16 bf16x8 __attribute__((ext_vector_type(8)));
typedef float  f32x4  __attribute__((ext_vector_type(4)));

__device__ inline unsigned short f2bf(float f) {
  unsigned u = __float_as_uint(f);
  return (unsigned short)((u + 0x7FFFu + ((u >> 16) & 1u)) >> 16);
}
__device__ inline float bf2f(unsigned short h) {
  return __uint_as_float(((unsigned)h) << 16);
}

__device__ inline void gload_lds16(const void* g, void* l) {
  __builtin_amdgcn_global_load_lds(
      (const __attribute__((address_space(1))) unsigned int*)(uintptr_t)g,
      (__attribute__((address_space(3))) unsigned int*)(uint32_t)(uintptr_t)l,
      16, 0, 0);
}

__global__ void k_init_mm(unsigned* mm) {
  mm[0] = 0x7F800000u;  // +inf bits (running min)
  mm[1] = 0u;           // 0.0 bits (running max); distances >= 0
}

// src[rows][256] f32 -> dst bf16 split parts + row sum-of-squares.
// h written at element cols off_h0 and off_h1, l at off_l (within 768-wide row).
__global__ __launch_bounds__(64) void k_prep(const float* __restrict__ src,
                                             unsigned short* __restrict__ dst,
                                             float* __restrict__ sq,
                                             int off_h0, int off_h1, int off_l) {
  const int row  = blockIdx.x;
  const int lane = threadIdx.x;
  const float4 v = *(const float4*)(src + (size_t)row * IN_DIM + lane * 4);
  float s = v.x * v.x + v.y * v.y + v.z * v.z + v.w * v.w;
  #pragma unroll
  for (int m = 1; m < 64; m <<= 1) s += __shfl_xor(s, m, 64);
  ushort4 h, l;
  h.x = f2bf(v.x); h.y = f2bf(v.y); h.z = f2bf(v.z); h.w = f2bf(v.w);
  l.x = f2bf(v.x - bf2f(h.x)); l.y = f2bf(v.y - bf2f(h.y));
  l.z = f2bf(v.z - bf2f(h.z)); l.w = f2bf(v.w - bf2f(h.w));
  unsigned short* rb = dst + (size_t)row * KE;
  *(ushort4*)(rb + off_h0 + lane * 4) = h;
  *(ushort4*)(rb + off_h1 + lane * 4) = h;
  *(ushort4*)(rb + off_l  + lane * 4) = l;
  if (lane == 0) sq[row] = s;
}

// w[c][n][f] f32 -> Wt[f][n*512+c] bf16, via 64x64 LDS transpose tiles
__global__ __launch_bounds__(256) void k_prepw(const float* __restrict__ w,
                                               unsigned short* __restrict__ wt) {
  __shared__ float t[64][65];
  const int n  = blockIdx.x % 9;
  const int cb = blockIdx.x / 9;
  const int f0 = blockIdx.y * 64;
  const int tid = threadIdx.x;
  const int c = tid & 63, rb = tid >> 6;  // 4 rows per pass
  #pragma unroll
  for (int i = 0; i < 16; ++i) {
    const int r = rb + 4 * i;  // r = c-index within block
    t[r][c] = w[((size_t)(cb * 64 + r) * 9 + n) * OUT_DIM + f0 + c];
  }
  __syncthreads();
  #pragma unroll
  for (int i = 0; i < 16; ++i) {
    const int r = rb + 4 * i;  // r = f-index within block
    wt[(size_t)(f0 + r) * KTOT + n * 512 + cb * 64 + c] = f2bf(t[c][r]);
  }
}

// d[b][c] = sqrt(x2[b]+c2[c]-2*Aext@Bext^T) via bf16 MFMA (K=768, split precision)
// 128x64 tiles, 4 waves 2x2 (wave 64x32); also block min/max -> atomics
__global__ __launch_bounds__(256) void k_dist(const unsigned short* __restrict__ Ae,
                                              const unsigned short* __restrict__ Be,
                                              const float* __restrict__ x2,
                                              const float* __restrict__ c2,
                                              float* __restrict__ d,
                                              unsigned* __restrict__ mm) {
  __shared__ unsigned short As[128 * 64];
  __shared__ unsigned short Bs[64 * 64];
  __shared__ float rmin[4], rmax[4];
  const int tid  = threadIdx.x;
  const int bm0  = blockIdx.x * 128;
  const int bc0  = blockIdx.y * 64;
  const int lane = tid & 63;
  const int wid  = tid >> 6;
  const int wm = wid >> 1, wn = wid & 1;
  f32x4 acc[4][2] = {};
  const char* gA = (const char*)Ae;
  const char* gB = (const char*)Be;
  char* lA = (char*)As;
  char* lB = (char*)Bs;
  for (int step = 0; step < KE / 64; ++step) {
    const int k0 = step * 64;
    __syncthreads();
    #pragma unroll
    for (int p = 0; p < 4; ++p) {
      const int flat = p * 4096 + tid * 16;
      const int row = flat >> 7, cb = flat & 127;
      const int srcb = cb ^ ((row & 7) << 4);
      gload_lds16(gA + ((size_t)(bm0 + row) * KE + k0) * 2 + srcb, lA + flat);
    }
    #pragma unroll
    for (int p = 0; p < 2; ++p) {
      const int flat = p * 4096 + tid * 16;
      const int row = flat >> 7, cb = flat & 127;
      const int srcb = cb ^ ((row & 7) << 4);
      gload_lds16(gB + ((size_t)(bc0 + row) * KE + k0) * 2 + srcb, lB + flat);
    }
    __syncthreads();
    #pragma unroll
    for (int ks = 0; ks < 2; ++ks) {
      bf16x8 af[4], bfr[2];
      const int kb = ks * 64 + (lane >> 4) * 16;
      #pragma unroll
      for (int m = 0; m < 4; ++m) {
        const int row = wm * 64 + m * 16 + (lane & 15);
        af[m] = *(const bf16x8*)(lA + row * 128 + (kb ^ ((row & 7) << 4)));
      }
      #pragma unroll
      for (int n = 0; n < 2; ++n) {
        const int row = wn * 32 + n * 16 + (lane & 15);
        bfr[n] = *(const bf16x8*)(lB + row * 128 + (kb ^ ((row & 7) << 4)));
      }
      #pragma unroll
      for (int m = 0; m < 4; ++m)
        #pragma unroll
        for (int n = 0; n < 2; ++n)
          acc[m][n] = __builtin_amdgcn_mfma_f32_16x16x32_bf16(af[m], bfr[n], acc[m][n], 0, 0, 0);
    }
  }
  float lmin = 1e30f, lmax = -1e30f;
  #pragma unroll
  for (int m = 0; m < 4; ++m) {
    #pragma unroll
    for (int j = 0; j < 4; ++j) {
      const int row = bm0 + wm * 64 + m * 16 + (lane >> 4) * 4 + j;
      const float xs = x2[row];
      #pragma unroll
      for (int n = 0; n < 2; ++n) {
        const int col = bc0 + wn * 32 + n * 16 + (lane & 15);
        float d2 = xs + c2[col] - 2.0f * acc[m][n][j];
        float dd = sqrtf(fmaxf(d2, 0.0f));
        d[(size_t)row * NC + col] = dd;
        lmin = fminf(lmin, dd);
        lmax = fmaxf(lmax, dd);
      }
    }
  }
  #pragma unroll
  for (int m = 1; m < 64; m <<= 1) {
    lmin = fminf(lmin, __shfl_xor(lmin, m, 64));
    lmax = fmaxf(lmax, __shfl_xor(lmax, m, 64));
  }
  if (lane == 0) { rmin[wid] = lmin; rmax[wid] = lmax; }
  __syncthreads();
  if (tid == 0) {
    float m0 = fminf(fminf(rmin[0], rmin[1]), fminf(rmin[2], rmin[3]));
    float m1 = fmaxf(fmaxf(rmax[0], rmax[1]), fmaxf(rmax[2], rmax[3]));
    atomicMin(mm + 0, __float_as_uint(m0));
    atomicMax(mm + 1, __float_as_uint(m1));
  }
}

// Fused basis + GEMM: out[b,f] = sum_n sum_c P_n(t[b,c]) * w[c,n,f]
// K ordered n-major (k = n*512+c). 64x64 tile, 4 waves (each 16 rows x 64 cols).
// Legendre recurrence state lives in registers; Wt staged per c-block (9n x 64f x 64c = 72KB).
__global__ __launch_bounds__(256) void k_fused(const float* __restrict__ d,
                                               const unsigned short* __restrict__ Wt,
                                               const unsigned* __restrict__ mm,
                                               float* __restrict__ out) {
  __shared__ char lB[73728];  // static: 72KB dynamic LDS would need hipFuncSetAttribute
  const int tid  = threadIdx.x;
  const int lane = tid & 63;
  const int w    = tid >> 6;
  const int bm0  = blockIdx.x * 64;
  const int f0   = blockIdx.y * 64;
  const float dmin = __uint_as_float(mm[0]);
  const float dmax = __uint_as_float(mm[1]);
  const float inv  = 2.0f / (dmax - dmin);
  f32x4 acc[4] = {};
  const int rowd = bm0 + w * 16 + (lane & 15);
  const int sw   = (lane & 7) << 4;  // B-row swizzle: rows are nf*16+(lane&15), row&7 == lane&7

  for (int cb = 0; cb < 8; ++cb) {
    __syncthreads();  // previous iteration's Bs reads complete
    // d loads first (register), then async staging
    float4 dv[4];
    {
      const float* dp = d + (size_t)rowd * NC + cb * 64 + (lane >> 4) * 8;
      dv[0] = *(const float4*)(dp);
      dv[1] = *(const float4*)(dp + 4);
      dv[2] = *(const float4*)(dp + 32);
      dv[3] = *(const float4*)(dp + 36);
    }
    #pragma unroll
    for (int p = 0; p < 18; ++p) {
      const int flat = p * 4096 + tid * 16;
      const int n    = flat >> 13;
      const int rem  = flat & 8191;
      const int row  = rem >> 7;
      const int cbyt = rem & 127;
      const int srcb = cbyt ^ ((row & 7) << 4);
      gload_lds16((const char*)Wt + ((size_t)(f0 + row) * KTOT + n * 512 + cb * 64) * 2 + srcb,
                  lB + flat);
    }
    float t_[16];
    #pragma unroll
    for (int q = 0; q < 4; ++q) {
      t_[q * 4 + 0] = (dv[q].x - dmin) * inv - 1.0f;
      t_[q * 4 + 1] = (dv[q].y - dmin) * inv - 1.0f;
      t_[q * 4 + 2] = (dv[q].z - dmin) * inv - 1.0f;
      t_[q * 4 + 3] = (dv[q].w - dmin) * inv - 1.0f;
    }
    __syncthreads();  // Bs staged

    // per n-step: 4 nf x 2 ks MFMA; A-frag slot s = ks*8+j <-> t_[s]
    #define MFMA_N(nn, af0, af1)                                                      \
      {                                                                               \
        _Pragma("unroll")                                                             \
        for (int nf = 0; nf < 4; ++nf) {                                              \
          const int rbase = (nn) * 8192 + (nf * 16 + (lane & 15)) * 128;              \
          bf16x8 b0 = *(const bf16x8*)(lB + rbase + (((lane >> 4) * 16) ^ sw));       \
          bf16x8 b1 = *(const bf16x8*)(lB + rbase + ((64 + (lane >> 4) * 16) ^ sw));  \
          acc[nf] = __builtin_amdgcn_mfma_f32_16x16x32_bf16(af0, b0, acc[nf], 0, 0, 0); \
          acc[nf] = __builtin_amdgcn_mfma_f32_16x16x32_bf16(af1, b1, acc[nf], 0, 0, 0); \
        }                                                                             \
      }

    float pa[16], pb[16];
    {  // n = 0: P0 = 1
      bf16x8 a0, a1;
      #pragma unroll
      for (int j = 0; j < 8; ++j) { a0[j] = (__bf16)1.0f; a1[j] = (__bf16)1.0f; }
      MFMA_N(0, a0, a1)
    }
    {  // n = 1: P1 = t
      bf16x8 a0, a1;
      #pragma unroll
      for (int j = 0; j < 8; ++j) { a0[j] = (__bf16)t_[j]; a1[j] = (__bf16)t_[8 + j]; }
      MFMA_N(1, a0, a1)
      #pragma unroll
      for (int s = 0; s < 16; ++s) { pa[s] = 1.0f; pb[s] = t_[s]; }
    }
    #pragma unroll
    for (int n = 2; n <= 8; ++n) {
      const float an = (2.0f * n - 1.0f) / (float)n;
      const float bn = (float)(n - 1) / (float)n;
      float pc[16];
      #pragma unroll
      for (int s = 0; s < 16; ++s) pc[s] = an * t_[s] * pb[s] - bn * pa[s];
      bf16x8 a0, a1;
      #pragma unroll
      for (int j = 0; j < 8; ++j) { a0[j] = (__bf16)pc[j]; a1[j] = (__bf16)pc[8 + j]; }
      MFMA_N(n, a0, a1)
      #pragma unroll
      for (int s = 0; s < 16; ++s) { pa[s] = pb[s]; pb[s] = pc[s]; }
    }
    #undef MFMA_N
  }
  // epilogue: direct stores (each block owns its 64x64 output tile)
  #pragma unroll
  for (int nf = 0; nf < 4; ++nf) {
    const int col = f0 + nf * 16 + (lane & 15);
    #pragma unroll
    for (int j = 0; j < 4; ++j) {
      const int row = bm0 + w * 16 + (lane >> 4) * 4 + j;
      out[(size_t)row * OUT_DIM + col] = acc[nf][j];
    }
  }
}

extern "C" void kernel_launch(void* const* d_in, const int* in_sizes, int n_in,
                              void* d_out, int out_size, void* d_ws, size_t ws_size,
                              hipStream_t stream) {
  const float* x   = (const float*)d_in[0];
  const float* cen = (const float*)d_in[1];
  const float* w   = (const float*)d_in[2];
  float* out = (float*)d_out;
  char* ws = (char*)d_ws;

  unsigned*       mm = (unsigned*)(ws + OFF_MM);
  float*          x2 = (float*)(ws + OFF_X2);
  float*          c2 = (float*)(ws + OFF_C2);
  unsigned short* Ae = (unsigned short*)(ws + OFF_AE);
  unsigned short* Be = (unsigned short*)(ws + OFF_BE);
  unsigned short* wt = (unsigned short*)(ws + OFF_WT);
  float*          dd = (float*)(ws + OFF_D);

  k_init_mm<<<1, 1, 0, stream>>>(mm);
  // Aext = [xh | xl | xh], Bext = [ch | ch | cl] -> A.B^T = xh.ch + xl.ch + xh.cl
  k_prep<<<BATCH, 64, 0, stream>>>(x,   Ae, x2, 0, 512, 256);
  k_prep<<<NC,    64, 0, stream>>>(cen, Be, c2, 0, 256, 512);
  k_prepw<<<dim3(72, 4), 256, 0, stream>>>(w, wt);
  k_dist<<<dim3(BATCH / 128, NC / 64), 256, 0, stream>>>(Ae, Be, x2, c2, dd, mm);
  k_fused<<<dim3(BATCH / 64, OUT_DIM / 64), 256, 0, stream>>>(dd, wt, mm, out);
}